// Round 2
// baseline (988.612 us; speedup 1.0000x reference)
//
#include <hip/hip_runtime.h>
#include <cstdint>
#include <cstddef>

// Problem constants (from reference)
#define NDST0 67584
#define NDST1 6144
#define NDST2 1024
#define NEDGE0 1013760
#define NEDGE1 61440
#define NEDGE2 5120
#define F0 128   // IN_FEATS
#define F1 256   // N_HIDDEN
#define NCLS 47

typedef unsigned short ushort_t;
typedef __attribute__((ext_vector_type(8))) short short8;       // 8 bf16 (4 VGPRs) - MFMA A/B frag
typedef __attribute__((ext_vector_type(8))) unsigned short ushortx8;
typedef __attribute__((ext_vector_type(4))) float floatx4;      // MFMA C/D frag

// ---- bf16 <-> f32 helpers (RNE, no NaN inputs here) ----
__device__ __forceinline__ ushort_t f2bf(float f) {
    union { float f; unsigned u; } v; v.f = f;
    unsigned r = v.u + 0x7fffu + ((v.u >> 16) & 1u);
    return (ushort_t)(r >> 16);
}
__device__ __forceinline__ float bf2f(ushort_t u) {
    union { unsigned u; float f; } v; v.u = ((unsigned)u) << 16;
    return v.f;
}

// async global->LDS, 16B per lane (global_load_lds_dwordx4)
__device__ __forceinline__ void async_copy16(ushort_t* lds, const ushort_t* g) {
    __builtin_amdgcn_global_load_lds(
        (const __attribute__((address_space(1))) unsigned*)(g),
        (__attribute__((address_space(3))) unsigned*)(lds),
        16, 0, 0);
}

// ---------------------------------------------------------------------------
// 0) Fused prep: sel_convert (blocks [0,8448)) + wprep (blocks [8448,9472))
//    + hist (blocks [9472,10496), grid-stride). All independent work items;
//    memset of cnt precedes this kernel.
// ---------------------------------------------------------------------------
#define SEL_BLOCKS  8448     // NDST0 * (F0/4) / 256
#define WPREP_BLOCKS 1024    // (256*256 + 256*512 + 128*512) / 256
#define HIST_BLOCKS 1024

__device__ __forceinline__ void wprep_seg(
    const float* __restrict__ Ws, const float* __restrict__ Wn,
    int din, int dout, int id, ushort_t* __restrict__ Bt)
{
    const int K2 = 2 * din;
    const int n = id / K2;
    const int k2 = id - n * K2;
    float v = 0.f;
    if (n < dout)
        v = (k2 < din) ? Ws[(size_t)k2 * dout + n] : Wn[(size_t)(k2 - din) * dout + n];
    Bt[id] = f2bf(v);
}

__global__ __launch_bounds__(256) void prep_all(
    // sel_convert
    const float* __restrict__ emb, const int* __restrict__ input_nodes,
    ushort_t* __restrict__ embsel,
    // wprep
    const float* __restrict__ Ws0, const float* __restrict__ Wn0,
    const float* __restrict__ Ws1, const float* __restrict__ Wn1,
    const float* __restrict__ Ws2, const float* __restrict__ Wn2,
    ushort_t* __restrict__ Bt0, ushort_t* __restrict__ Bt1,
    ushort_t* __restrict__ Bt2,
    // hist
    const int* __restrict__ dst0, const int* __restrict__ dst1,
    const int* __restrict__ dst2,
    int* __restrict__ cnt0, int* __restrict__ cnt1, int* __restrict__ cnt2)
{
    const int b = blockIdx.x;
    const int tid = threadIdx.x;
    if (b < SEL_BLOCKS) {
        // embsel[m][k] = bf16(emb[input_nodes[m]][k]); one float4 quad/thread
        const int q = b * 256 + tid;                  // quad index
        const int qpr = F0 >> 2;                      // quads per row = 32
        if (q >= NDST0 * qpr) return;
        const int m = q >> 5;
        const int c = q & 31;
        const int row = input_nodes[m];
        const float4 v = *(const float4*)(emb + (size_t)row * F0 + c * 4);
        ushort4 o;
        o.x = f2bf(v.x); o.y = f2bf(v.y); o.z = f2bf(v.z); o.w = f2bf(v.w);
        *(ushort4*)(embsel + (size_t)m * F0 + c * 4) = o;
    } else if (b < SEL_BLOCKS + WPREP_BLOCKS) {
        const int S0 = 256 * 256, S1 = 256 * 512, S2 = 128 * 512;
        const int id = (b - SEL_BLOCKS) * 256 + tid;
        if (id < S0)                 wprep_seg(Ws0, Wn0, F0, 256,  id,           Bt0);
        else if (id < S0 + S1)       wprep_seg(Ws1, Wn1, F1, 256,  id - S0,      Bt1);
        else if (id < S0 + S1 + S2)  wprep_seg(Ws2, Wn2, F1, NCLS, id - S0 - S1, Bt2);
    } else {
        const int total = NEDGE0 + NEDGE1 + NEDGE2;
        int i = (b - SEL_BLOCKS - WPREP_BLOCKS) * 256 + tid;
        const int stride = HIST_BLOCKS * 256;
        for (; i < total; i += stride) {
            if (i < NEDGE0)                 atomicAdd(&cnt0[dst0[i]], 1);
            else if (i < NEDGE0 + NEDGE1)   atomicAdd(&cnt1[dst1[i - NEDGE0]], 1);
            else                            atomicAdd(&cnt2[dst2[i - NEDGE0 - NEDGE1]], 1);
        }
    }
}

// ---------------------------------------------------------------------------
// 2) Fused single-block exclusive scans: block b handles layer b
// ---------------------------------------------------------------------------
__global__ __launch_bounds__(1024) void scan_all(
    const int* __restrict__ c0, int* __restrict__ r0, int* __restrict__ w0,
    const int* __restrict__ c1, int* __restrict__ r1, int* __restrict__ w1,
    const int* __restrict__ c2, int* __restrict__ r2, int* __restrict__ w2)
{
    __shared__ int sums[1024];
    const int* cnt; int* rs; int* work; int n;
    if (blockIdx.x == 0)      { cnt = c0; rs = r0; work = w0; n = NDST0; }
    else if (blockIdx.x == 1) { cnt = c1; rs = r1; work = w1; n = NDST1; }
    else                      { cnt = c2; rs = r2; work = w2; n = NDST2; }

    const int tid = threadIdx.x;
    const int L = (n + 1023) >> 10;
    const int lo = tid * L;
    const int hi = (lo + L < n) ? (lo + L) : n;
    int s = 0;
    for (int i = lo; i < hi; ++i) s += cnt[i];
    sums[tid] = s;
    __syncthreads();
    int v = s;
    for (int off = 1; off < 1024; off <<= 1) {
        int t = (tid >= off) ? sums[tid - off] : 0;
        __syncthreads();
        v += t;
        sums[tid] = v;
        __syncthreads();
    }
    int run = v - s;
    for (int i = lo; i < hi; ++i) {
        rs[i] = run;
        work[i] = run;
        run += cnt[i];
    }
    if (tid == 1023) rs[n] = run;
}

// ---------------------------------------------------------------------------
// 3) Fused scatter of edges into dst-sorted order (layer 0 resolves
//    input_nodes once so the gather reads emb directly)
// ---------------------------------------------------------------------------
__global__ __launch_bounds__(256) void fill_all(
    const int* __restrict__ src0, const int* __restrict__ dst0,
    const int* __restrict__ src1, const int* __restrict__ dst1,
    const int* __restrict__ src2, const int* __restrict__ dst2,
    const int* __restrict__ idx,
    int* __restrict__ work0, int* __restrict__ work1, int* __restrict__ work2,
    int* __restrict__ esrc0, int* __restrict__ esrc1, int* __restrict__ esrc2)
{
    int e = blockIdx.x * 256 + threadIdx.x;
    if (e < NEDGE0) {
        const int s = src0[e];
        const int row = idx[s];
        const int p = atomicAdd(&work0[dst0[e]], 1);
        esrc0[p] = row;
    } else if (e < NEDGE0 + NEDGE1) {
        e -= NEDGE0;
        const int p = atomicAdd(&work1[dst1[e]], 1);
        esrc1[p] = src1[e];
    } else if (e < NEDGE0 + NEDGE1 + NEDGE2) {
        e -= NEDGE0 + NEDGE1;
        const int p = atomicAdd(&work2[dst2[e]], 1);
        esrc2[p] = src2[e];
    }
}

// ---------------------------------------------------------------------------
// 4a) Per-dst gather-accumulate from fp32 table -> bf16 agg (pre-scaled 1/deg)
//     lanes = feat/4, float4 per lane. Unroll-4 for load ILP.
// ---------------------------------------------------------------------------
__global__ __launch_bounds__(256) void gather_f32(
    const float* __restrict__ table, const int* __restrict__ esrc,
    const int* __restrict__ rs, const int* __restrict__ cnt,
    int nd, int feat, int lshift, ushort_t* __restrict__ agg)
{
    const int lanes = 1 << lshift;
    const int gpb = 256 >> lshift;
    const int d = blockIdx.x * gpb + ((int)threadIdx.x >> lshift);
    if (d >= nd) return;
    const int lane = (int)threadIdx.x & (lanes - 1);
    const int start = rs[d];
    const int c = cnt[d];
    const float* tb = table + (size_t)lane * 4;
    float4 acc = make_float4(0.f, 0.f, 0.f, 0.f);
    int i = 0;
    for (; i + 3 < c; i += 4) {
        const int r0 = esrc[start + i];
        const int r1 = esrc[start + i + 1];
        const int r2 = esrc[start + i + 2];
        const int r3 = esrc[start + i + 3];
        const float4 v0 = *(const float4*)(tb + (size_t)r0 * feat);
        const float4 v1 = *(const float4*)(tb + (size_t)r1 * feat);
        const float4 v2 = *(const float4*)(tb + (size_t)r2 * feat);
        const float4 v3 = *(const float4*)(tb + (size_t)r3 * feat);
        acc.x += (v0.x + v1.x) + (v2.x + v3.x);
        acc.y += (v0.y + v1.y) + (v2.y + v3.y);
        acc.z += (v0.z + v1.z) + (v2.z + v3.z);
        acc.w += (v0.w + v1.w) + (v2.w + v3.w);
    }
    for (; i < c; ++i) {
        const int r0 = esrc[start + i];
        const float4 v0 = *(const float4*)(tb + (size_t)r0 * feat);
        acc.x += v0.x; acc.y += v0.y; acc.z += v0.z; acc.w += v0.w;
    }
    const float sc = 1.0f / fmaxf((float)c, 1.0f);
    ushort4 o;
    o.x = f2bf(acc.x * sc); o.y = f2bf(acc.y * sc);
    o.z = f2bf(acc.z * sc); o.w = f2bf(acc.w * sc);
    *(ushort4*)(agg + (size_t)d * feat + lane * 4) = o;
}

// ---------------------------------------------------------------------------
// 4b) Same, but table is bf16 (h1/h2). lanes = feat/8, ushort8 (16B) per lane.
// ---------------------------------------------------------------------------
__global__ __launch_bounds__(256) void gather_bf16(
    const ushort_t* __restrict__ table, const int* __restrict__ esrc,
    const int* __restrict__ rs, const int* __restrict__ cnt,
    int nd, int feat, int lshift, ushort_t* __restrict__ agg)
{
    const int lanes = 1 << lshift;          // feat/8
    const int gpb = 256 >> lshift;
    const int d = blockIdx.x * gpb + ((int)threadIdx.x >> lshift);
    if (d >= nd) return;
    const int lane = (int)threadIdx.x & (lanes - 1);
    const int start = rs[d];
    const int c = cnt[d];
    const ushort_t* tb = table + (size_t)lane * 8;
    float acc[8] = {0.f, 0.f, 0.f, 0.f, 0.f, 0.f, 0.f, 0.f};
    int i = 0;
    for (; i + 1 < c; i += 2) {
        const int r0 = esrc[start + i];
        const int r1 = esrc[start + i + 1];
        const ushortx8 v0 = *(const ushortx8*)(tb + (size_t)r0 * feat);
        const ushortx8 v1 = *(const ushortx8*)(tb + (size_t)r1 * feat);
        #pragma unroll
        for (int j = 0; j < 8; ++j) acc[j] += bf2f(v0[j]) + bf2f(v1[j]);
    }
    if (i < c) {
        const int r0 = esrc[start + i];
        const ushortx8 v0 = *(const ushortx8*)(tb + (size_t)r0 * feat);
        #pragma unroll
        for (int j = 0; j < 8; ++j) acc[j] += bf2f(v0[j]);
    }
    const float sc = 1.0f / fmaxf((float)c, 1.0f);
    ushortx8 o;
    #pragma unroll
    for (int j = 0; j < 8; ++j) o[j] = f2bf(acc[j] * sc);
    *(ushortx8*)(agg + (size_t)d * feat + lane * 8) = o;
}

// ---------------------------------------------------------------------------
// MFMA GEMM (m97 structure): 128x128 tile, 4 waves x (64x64), BK=32 bf16.
//   out[m,n] = act( sum_k Aself[m,k]*Wself[k,n] + sum_k Aneigh[m,k]*Wneigh[k,n] + b[n] )
// A-phase: k0 < din -> Aself, else Aneigh (phase-uniform pointer switch).
// B from pre-transposed Wcat_t [npad>=128 rows][K2], staged coalesced.
// ---------------------------------------------------------------------------
__global__ __launch_bounds__(256) void mfma_gemm(
    const ushort_t* __restrict__ Aself, const ushort_t* __restrict__ Aneigh,
    const ushort_t* __restrict__ Bt, const float* __restrict__ bias,
    void* __restrict__ outp, int din, int dout, int out_bf16, int do_relu)
{
    __shared__ ushort_t As[128 * 32];
    __shared__ ushort_t Bs[128 * 32];

    const int tid  = threadIdx.x;
    const int wave = tid >> 6;
    const int lane = tid & 63;
    const int m0 = blockIdx.x * 128;
    const int n0 = blockIdx.y * 128;
    const int wm = (wave & 1) * 64;
    const int wn = (wave >> 1) * 64;

    // staging: per wave 2 instrs x (16 rows x 64B); lane -> row l>>2, chunk l&3
    const int arow = lane >> 2;
    const int achk = (lane & 3) * 8;     // ushort offset of 16B chunk

    const int K2 = 2 * din;

    floatx4 acc[4][4];
    const floatx4 zero = {0.f, 0.f, 0.f, 0.f};
    #pragma unroll
    for (int i = 0; i < 4; ++i)
        #pragma unroll
        for (int j = 0; j < 4; ++j) acc[i][j] = zero;

    const int fr = lane & 15;
    const int fq = (lane >> 4) * 8;      // ushort offset of k-chunk in frag row

    for (int k0 = 0; k0 < K2; k0 += 32) {
        const ushort_t* Abase = (k0 < din) ? (Aself + k0) : (Aneigh + (k0 - din));
        #pragma unroll
        for (int i = 0; i < 2; ++i) {
            const int rg = (wave * 2 + i) * 16 + arow;           // tile row 0..127
            async_copy16(&As[rg * 32 + achk],
                         Abase + (size_t)(m0 + rg) * din + achk);
            async_copy16(&Bs[rg * 32 + achk],
                         Bt + (size_t)(n0 + rg) * K2 + k0 + achk);
        }
        __syncthreads();   // drains vmcnt: staged data visible

        short8 a[4], b[4];
        #pragma unroll
        for (int f = 0; f < 4; ++f) {
            a[f] = *(const short8*)&As[(wm + f * 16 + fr) * 32 + fq];
            b[f] = *(const short8*)&Bs[(wn + f * 16 + fr) * 32 + fq];
        }
        #pragma unroll
        for (int fm = 0; fm < 4; ++fm)
            #pragma unroll
            for (int fn = 0; fn < 4; ++fn)
                acc[fm][fn] = __builtin_amdgcn_mfma_f32_16x16x32_bf16(
                    a[fm], b[fn], acc[fm][fn], 0, 0, 0);
        __syncthreads();   // all waves done reading before next stage
    }

    // epilogue: C/D layout col=lane&15, row=(lane>>4)*4+reg  [m89/m91]
    const int erow = (lane >> 4) * 4;
    const int ecol = lane & 15;
    #pragma unroll
    for (int fn = 0; fn < 4; ++fn) {
        const int gn = n0 + wn + fn * 16 + ecol;
        if (gn >= dout) continue;
        const float bv = bias[gn];
        #pragma unroll
        for (int fm = 0; fm < 4; ++fm) {
            #pragma unroll
            for (int r = 0; r < 4; ++r) {
                const size_t gm = m0 + wm + fm * 16 + erow + r;
                float v = acc[fm][fn][r] + bv;
                if (do_relu) v = fmaxf(v, 0.f);
                if (out_bf16) ((ushort_t*)outp)[gm * dout + gn] = f2bf(v);
                else          ((float*)outp)[gm * dout + gn] = v;
            }
        }
    }
}

// ---------------------------------------------------------------------------
extern "C" void kernel_launch(void* const* d_in, const int* in_sizes, int n_in,
                              void* d_out, int out_size, void* d_ws, size_t ws_size,
                              hipStream_t stream)
{
    const float* emb         = (const float*)d_in[0];
    const int*   input_nodes = (const int*)d_in[1];
    const int*   src0 = (const int*)d_in[2];
    const int*   dst0 = (const int*)d_in[3];
    const int*   src1 = (const int*)d_in[4];
    const int*   dst1 = (const int*)d_in[5];
    const int*   src2 = (const int*)d_in[6];
    const int*   dst2 = (const int*)d_in[7];
    const float* Ws0 = (const float*)d_in[8];
    const float* Wn0 = (const float*)d_in[9];
    const float* b0  = (const float*)d_in[10];
    const float* Ws1 = (const float*)d_in[11];
    const float* Wn1 = (const float*)d_in[12];
    const float* b1  = (const float*)d_in[13];
    const float* Ws2 = (const float*)d_in[14];
    const float* Wn2 = (const float*)d_in[15];
    const float* b2  = (const float*)d_in[16];
    float* out = (float*)d_out;

    // ---- Workspace layout (bf16 activations + int CSR scratch) ----
    ushort_t* us     = (ushort_t*)d_ws;
    ushort_t* embsel = us;                                   // 67584*128
    ushort_t* agg0   = embsel + (size_t)NDST0 * F0;          // 67584*128
    ushort_t* h1     = agg0 + (size_t)NDST0 * F0;            // 67584*256
    ushort_t* agg1   = h1 + (size_t)NDST0 * F1;              // 6144*256
    ushort_t* h2     = agg1 + (size_t)NDST1 * F1;            // 6144*256
    ushort_t* agg2   = h2 + (size_t)NDST1 * F1;              // 1024*256
    ushort_t* Bt0    = agg2 + (size_t)NDST2 * F1;            // 256 x 256
    ushort_t* Bt1    = Bt0 + 256 * 256;                      // 256 x 512
    ushort_t* Bt2    = Bt1 + 256 * 512;                      // 128 x 512 (rows 47..127 zero)

    int* ip   = (int*)(Bt2 + 128 * 512);
    int* cnt0 = ip;  ip += NDST0;
    int* cnt1 = ip;  ip += NDST1;
    int* cnt2 = ip;  ip += NDST2;
    const size_t zero_bytes = (size_t)(NDST0 + NDST1 + NDST2) * sizeof(int);
    int* rs0   = ip; ip += NDST0 + 1;
    int* work0 = ip; ip += NDST0;
    int* rs1   = ip; ip += NDST1 + 1;
    int* work1 = ip; ip += NDST1;
    int* rs2   = ip; ip += NDST2 + 1;
    int* work2 = ip; ip += NDST2;
    int* esrc0 = ip; ip += NEDGE0;
    int* esrc1 = ip; ip += NEDGE1;
    int* esrc2 = ip; ip += NEDGE2;

    hipMemsetAsync(cnt0, 0, zero_bytes, stream);

    // Fused prep: sel_convert + wprep + hist (after cnt memset)
    prep_all<<<SEL_BLOCKS + WPREP_BLOCKS + HIST_BLOCKS, 256, 0, stream>>>(
        emb, input_nodes, embsel,
        Ws0, Wn0, Ws1, Wn1, Ws2, Wn2, Bt0, Bt1, Bt2,
        dst0, dst1, dst2, cnt0, cnt1, cnt2);

    scan_all<<<3, 1024, 0, stream>>>(cnt0, rs0, work0, cnt1, rs1, work1, cnt2, rs2, work2);
    fill_all<<<(NEDGE0 + NEDGE1 + NEDGE2 + 255) / 256, 256, 0, stream>>>(
        src0, dst0, src1, dst1, src2, dst2, input_nodes,
        work0, work1, work2, esrc0, esrc1, esrc2);

    // ---- Layer 0: din=128 ----
    gather_f32<<<NDST0 / 8, 256, 0, stream>>>(emb, esrc0, rs0, cnt0, NDST0, F0, 5, agg0);
    mfma_gemm<<<dim3(NDST0 / 128, 256 / 128), 256, 0, stream>>>(
        embsel, agg0, Bt0, b0, h1, F0, 256, /*out_bf16=*/1, /*relu=*/1);

    // ---- Layer 1: din=256 ----
    gather_bf16<<<NDST1 / 8, 256, 0, stream>>>(h1, esrc1, rs1, cnt1, NDST1, F1, 5, agg1);
    mfma_gemm<<<dim3(NDST1 / 128, 256 / 128), 256, 0, stream>>>(
        h1, agg1, Bt1, b1, h2, F1, 256, /*out_bf16=*/1, /*relu=*/1);

    // ---- Layer 2: din=256, dout=47, no relu, fp32 out ----
    gather_bf16<<<NDST2 / 8, 256, 0, stream>>>(h2, esrc2, rs2, cnt2, NDST2, F1, 5, agg2);
    mfma_gemm<<<dim3(NDST2 / 128, 1), 256, 0, stream>>>(
        h2, agg2, Bt2, b2, out, F1, NCLS, /*out_bf16=*/0, /*relu=*/0);
}

// Round 3
// 923.490 us; speedup vs baseline: 1.0705x; 1.0705x over previous
//
#include <hip/hip_runtime.h>
#include <cstdint>
#include <cstddef>

// Problem constants (from reference)
#define NDST0 67584
#define NDST1 6144
#define NDST2 1024
#define NEDGE0 1013760
#define NEDGE1 61440
#define NEDGE2 5120
#define F0 128   // IN_FEATS
#define F1 256   // N_HIDDEN
#define NCLS 47

typedef unsigned short ushort_t;
typedef __attribute__((ext_vector_type(8))) short short8;       // 8 bf16 (4 VGPRs) - MFMA A/B frag
typedef __attribute__((ext_vector_type(8))) unsigned short ushortx8;
typedef __attribute__((ext_vector_type(4))) float floatx4;      // MFMA C/D frag

// ---- bf16 <-> f32 helpers (RNE, no NaN inputs here) ----
__device__ __forceinline__ ushort_t f2bf(float f) {
    union { float f; unsigned u; } v; v.f = f;
    unsigned r = v.u + 0x7fffu + ((v.u >> 16) & 1u);
    return (ushort_t)(r >> 16);
}
__device__ __forceinline__ float bf2f(ushort_t u) {
    union { unsigned u; float f; } v; v.u = ((unsigned)u) << 16;
    return v.f;
}

// async global->LDS, 16B per lane (global_load_lds_dwordx4)
__device__ __forceinline__ void async_copy16(ushort_t* lds, const ushort_t* g) {
    __builtin_amdgcn_global_load_lds(
        (const __attribute__((address_space(1))) unsigned*)(g),
        (__attribute__((address_space(3))) unsigned*)(lds),
        16, 0, 0);
}

// ---------------------------------------------------------------------------
// 0) Fused prep: sel_convert (blocks [0,8448)) + wprep (blocks [8448,9472))
//    + hist-with-rank (blocks [9472,10496), grid-stride).
//    hist's atomicAdd old-value IS the edge's rank within its dst segment —
//    stored to rank[] (coalesced) so fill needs no atomics at all.
// ---------------------------------------------------------------------------
#define SEL_BLOCKS  8448     // NDST0 * (F0/4) / 256
#define WPREP_BLOCKS 1024    // (256*256 + 256*512 + 128*512) / 256
#define HIST_BLOCKS 1024

__device__ __forceinline__ void wprep_seg(
    const float* __restrict__ Ws, const float* __restrict__ Wn,
    int din, int dout, int id, ushort_t* __restrict__ Bt)
{
    const int K2 = 2 * din;
    const int n = id / K2;
    const int k2 = id - n * K2;
    float v = 0.f;
    if (n < dout)
        v = (k2 < din) ? Ws[(size_t)k2 * dout + n] : Wn[(size_t)(k2 - din) * dout + n];
    Bt[id] = f2bf(v);
}

__global__ __launch_bounds__(256) void prep_all(
    // sel_convert
    const float* __restrict__ emb, const int* __restrict__ input_nodes,
    ushort_t* __restrict__ embsel,
    // wprep
    const float* __restrict__ Ws0, const float* __restrict__ Wn0,
    const float* __restrict__ Ws1, const float* __restrict__ Wn1,
    const float* __restrict__ Ws2, const float* __restrict__ Wn2,
    ushort_t* __restrict__ Bt0, ushort_t* __restrict__ Bt1,
    ushort_t* __restrict__ Bt2,
    // hist + rank
    const int* __restrict__ dst0, const int* __restrict__ dst1,
    const int* __restrict__ dst2,
    int* __restrict__ cnt0, int* __restrict__ cnt1, int* __restrict__ cnt2,
    int* __restrict__ rank0, int* __restrict__ rank1, int* __restrict__ rank2)
{
    const int b = blockIdx.x;
    const int tid = threadIdx.x;
    if (b < SEL_BLOCKS) {
        // embsel[m][k] = bf16(emb[input_nodes[m]][k]); one float4 quad/thread
        const int q = b * 256 + tid;                  // quad index
        const int qpr = F0 >> 2;                      // quads per row = 32
        if (q >= NDST0 * qpr) return;
        const int m = q >> 5;
        const int c = q & 31;
        const int row = input_nodes[m];
        const float4 v = *(const float4*)(emb + (size_t)row * F0 + c * 4);
        ushort4 o;
        o.x = f2bf(v.x); o.y = f2bf(v.y); o.z = f2bf(v.z); o.w = f2bf(v.w);
        *(ushort4*)(embsel + (size_t)m * F0 + c * 4) = o;
    } else if (b < SEL_BLOCKS + WPREP_BLOCKS) {
        const int S0 = 256 * 256, S1 = 256 * 512, S2 = 128 * 512;
        const int id = (b - SEL_BLOCKS) * 256 + tid;
        if (id < S0)                 wprep_seg(Ws0, Wn0, F0, 256,  id,           Bt0);
        else if (id < S0 + S1)       wprep_seg(Ws1, Wn1, F1, 256,  id - S0,      Bt1);
        else if (id < S0 + S1 + S2)  wprep_seg(Ws2, Wn2, F1, NCLS, id - S0 - S1, Bt2);
    } else {
        const int total = NEDGE0 + NEDGE1 + NEDGE2;
        int i = (b - SEL_BLOCKS - WPREP_BLOCKS) * 256 + tid;
        const int stride = HIST_BLOCKS * 256;
        for (; i < total; i += stride) {
            if (i < NEDGE0) {
                rank0[i] = atomicAdd(&cnt0[dst0[i]], 1);
            } else if (i < NEDGE0 + NEDGE1) {
                const int j = i - NEDGE0;
                rank1[j] = atomicAdd(&cnt1[dst1[j]], 1);
            } else {
                const int j = i - NEDGE0 - NEDGE1;
                rank2[j] = atomicAdd(&cnt2[dst2[j]], 1);
            }
        }
    }
}

// ---------------------------------------------------------------------------
// 2) Fused single-block exclusive scans: block b handles layer b (rs only)
// ---------------------------------------------------------------------------
__global__ __launch_bounds__(1024) void scan_all(
    const int* __restrict__ c0, int* __restrict__ r0,
    const int* __restrict__ c1, int* __restrict__ r1,
    const int* __restrict__ c2, int* __restrict__ r2)
{
    __shared__ int sums[1024];
    const int* cnt; int* rs; int n;
    if (blockIdx.x == 0)      { cnt = c0; rs = r0; n = NDST0; }
    else if (blockIdx.x == 1) { cnt = c1; rs = r1; n = NDST1; }
    else                      { cnt = c2; rs = r2; n = NDST2; }

    const int tid = threadIdx.x;
    const int L = (n + 1023) >> 10;
    const int lo = tid * L;
    const int hi = (lo + L < n) ? (lo + L) : n;
    int s = 0;
    for (int i = lo; i < hi; ++i) s += cnt[i];
    sums[tid] = s;
    __syncthreads();
    int v = s;
    for (int off = 1; off < 1024; off <<= 1) {
        int t = (tid >= off) ? sums[tid - off] : 0;
        __syncthreads();
        v += t;
        sums[tid] = v;
        __syncthreads();
    }
    int run = v - s;
    for (int i = lo; i < hi; ++i) {
        rs[i] = run;
        run += cnt[i];
    }
    if (tid == 1023) rs[n] = run;
}

// ---------------------------------------------------------------------------
// 3) Atomic-free scatter: p = rs[dst[e]] + rank[e] (rank captured in hist).
//    Layer 0 resolves input_nodes once so the gather reads emb directly.
// ---------------------------------------------------------------------------
__global__ __launch_bounds__(256) void fill_all(
    const int* __restrict__ src0, const int* __restrict__ dst0,
    const int* __restrict__ src1, const int* __restrict__ dst1,
    const int* __restrict__ src2, const int* __restrict__ dst2,
    const int* __restrict__ idx,
    const int* __restrict__ rs0, const int* __restrict__ rs1,
    const int* __restrict__ rs2,
    const int* __restrict__ rank0, const int* __restrict__ rank1,
    const int* __restrict__ rank2,
    int* __restrict__ esrc0, int* __restrict__ esrc1, int* __restrict__ esrc2)
{
    int e = blockIdx.x * 256 + threadIdx.x;
    if (e < NEDGE0) {
        const int row = idx[src0[e]];
        esrc0[rs0[dst0[e]] + rank0[e]] = row;
    } else if (e < NEDGE0 + NEDGE1) {
        e -= NEDGE0;
        esrc1[rs1[dst1[e]] + rank1[e]] = src1[e];
    } else if (e < NEDGE0 + NEDGE1 + NEDGE2) {
        e -= NEDGE0 + NEDGE1;
        esrc2[rs2[dst2[e]] + rank2[e]] = src2[e];
    }
}

// ---------------------------------------------------------------------------
// 4a) Per-dst gather-accumulate from fp32 table -> bf16 agg (pre-scaled 1/deg)
//     lanes = feat/4, float4 per lane. Unroll-4 for load ILP.
// ---------------------------------------------------------------------------
__global__ __launch_bounds__(256) void gather_f32(
    const float* __restrict__ table, const int* __restrict__ esrc,
    const int* __restrict__ rs, const int* __restrict__ cnt,
    int nd, int feat, int lshift, ushort_t* __restrict__ agg)
{
    const int lanes = 1 << lshift;
    const int gpb = 256 >> lshift;
    const int d = blockIdx.x * gpb + ((int)threadIdx.x >> lshift);
    if (d >= nd) return;
    const int lane = (int)threadIdx.x & (lanes - 1);
    const int start = rs[d];
    const int c = cnt[d];
    const float* tb = table + (size_t)lane * 4;
    float4 acc = make_float4(0.f, 0.f, 0.f, 0.f);
    int i = 0;
    for (; i + 3 < c; i += 4) {
        const int r0 = esrc[start + i];
        const int r1 = esrc[start + i + 1];
        const int r2 = esrc[start + i + 2];
        const int r3 = esrc[start + i + 3];
        const float4 v0 = *(const float4*)(tb + (size_t)r0 * feat);
        const float4 v1 = *(const float4*)(tb + (size_t)r1 * feat);
        const float4 v2 = *(const float4*)(tb + (size_t)r2 * feat);
        const float4 v3 = *(const float4*)(tb + (size_t)r3 * feat);
        acc.x += (v0.x + v1.x) + (v2.x + v3.x);
        acc.y += (v0.y + v1.y) + (v2.y + v3.y);
        acc.z += (v0.z + v1.z) + (v2.z + v3.z);
        acc.w += (v0.w + v1.w) + (v2.w + v3.w);
    }
    for (; i < c; ++i) {
        const int r0 = esrc[start + i];
        const float4 v0 = *(const float4*)(tb + (size_t)r0 * feat);
        acc.x += v0.x; acc.y += v0.y; acc.z += v0.z; acc.w += v0.w;
    }
    const float sc = 1.0f / fmaxf((float)c, 1.0f);
    ushort4 o;
    o.x = f2bf(acc.x * sc); o.y = f2bf(acc.y * sc);
    o.z = f2bf(acc.z * sc); o.w = f2bf(acc.w * sc);
    *(ushort4*)(agg + (size_t)d * feat + lane * 4) = o;
}

// ---------------------------------------------------------------------------
// 4b) Same, but table is bf16 (h1/h2). lanes = feat/8, ushort8 (16B) per lane.
// ---------------------------------------------------------------------------
__global__ __launch_bounds__(256) void gather_bf16(
    const ushort_t* __restrict__ table, const int* __restrict__ esrc,
    const int* __restrict__ rs, const int* __restrict__ cnt,
    int nd, int feat, int lshift, ushort_t* __restrict__ agg)
{
    const int lanes = 1 << lshift;          // feat/8
    const int gpb = 256 >> lshift;
    const int d = blockIdx.x * gpb + ((int)threadIdx.x >> lshift);
    if (d >= nd) return;
    const int lane = (int)threadIdx.x & (lanes - 1);
    const int start = rs[d];
    const int c = cnt[d];
    const ushort_t* tb = table + (size_t)lane * 8;
    float acc[8] = {0.f, 0.f, 0.f, 0.f, 0.f, 0.f, 0.f, 0.f};
    int i = 0;
    for (; i + 1 < c; i += 2) {
        const int r0 = esrc[start + i];
        const int r1 = esrc[start + i + 1];
        const ushortx8 v0 = *(const ushortx8*)(tb + (size_t)r0 * feat);
        const ushortx8 v1 = *(const ushortx8*)(tb + (size_t)r1 * feat);
        #pragma unroll
        for (int j = 0; j < 8; ++j) acc[j] += bf2f(v0[j]) + bf2f(v1[j]);
    }
    if (i < c) {
        const int r0 = esrc[start + i];
        const ushortx8 v0 = *(const ushortx8*)(tb + (size_t)r0 * feat);
        #pragma unroll
        for (int j = 0; j < 8; ++j) acc[j] += bf2f(v0[j]);
    }
    const float sc = 1.0f / fmaxf((float)c, 1.0f);
    ushortx8 o;
    #pragma unroll
    for (int j = 0; j < 8; ++j) o[j] = f2bf(acc[j] * sc);
    *(ushortx8*)(agg + (size_t)d * feat + lane * 8) = o;
}

// ---------------------------------------------------------------------------
// MFMA GEMM (m97 structure): 128x128 tile, 4 waves x (64x64), BK=32 bf16.
//   out[m,n] = act( sum_k Aself[m,k]*Wself[k,n] + sum_k Aneigh[m,k]*Wneigh[k,n] + b[n] )
// A-phase: k0 < din -> Aself, else Aneigh (phase-uniform pointer switch).
// B from pre-transposed Wcat_t [npad>=128 rows][K2], staged coalesced.
// Grid: x = n-tiles (fast; adjacent blocks share A-tile -> L2 hit), y = m-tiles.
// ---------------------------------------------------------------------------
__global__ __launch_bounds__(256) void mfma_gemm(
    const ushort_t* __restrict__ Aself, const ushort_t* __restrict__ Aneigh,
    const ushort_t* __restrict__ Bt, const float* __restrict__ bias,
    void* __restrict__ outp, int din, int dout, int out_bf16, int do_relu)
{
    __shared__ ushort_t As[128 * 32];
    __shared__ ushort_t Bs[128 * 32];

    const int tid  = threadIdx.x;
    const int wave = tid >> 6;
    const int lane = tid & 63;
    const int m0 = blockIdx.y * 128;
    const int n0 = blockIdx.x * 128;
    const int wm = (wave & 1) * 64;
    const int wn = (wave >> 1) * 64;

    // staging: per wave 2 instrs x (16 rows x 64B); lane -> row l>>2, chunk l&3
    const int arow = lane >> 2;
    const int achk = (lane & 3) * 8;     // ushort offset of 16B chunk

    const int K2 = 2 * din;

    floatx4 acc[4][4];
    const floatx4 zero = {0.f, 0.f, 0.f, 0.f};
    #pragma unroll
    for (int i = 0; i < 4; ++i)
        #pragma unroll
        for (int j = 0; j < 4; ++j) acc[i][j] = zero;

    const int fr = lane & 15;
    const int fq = (lane >> 4) * 8;      // ushort offset of k-chunk in frag row

    for (int k0 = 0; k0 < K2; k0 += 32) {
        const ushort_t* Abase = (k0 < din) ? (Aself + k0) : (Aneigh + (k0 - din));
        #pragma unroll
        for (int i = 0; i < 2; ++i) {
            const int rg = (wave * 2 + i) * 16 + arow;           // tile row 0..127
            async_copy16(&As[rg * 32 + achk],
                         Abase + (size_t)(m0 + rg) * din + achk);
            async_copy16(&Bs[rg * 32 + achk],
                         Bt + (size_t)(n0 + rg) * K2 + k0 + achk);
        }
        __syncthreads();   // drains vmcnt: staged data visible

        short8 a[4], b[4];
        #pragma unroll
        for (int f = 0; f < 4; ++f) {
            a[f] = *(const short8*)&As[(wm + f * 16 + fr) * 32 + fq];
            b[f] = *(const short8*)&Bs[(wn + f * 16 + fr) * 32 + fq];
        }
        #pragma unroll
        for (int fm = 0; fm < 4; ++fm)
            #pragma unroll
            for (int fn = 0; fn < 4; ++fn)
                acc[fm][fn] = __builtin_amdgcn_mfma_f32_16x16x32_bf16(
                    a[fm], b[fn], acc[fm][fn], 0, 0, 0);
        __syncthreads();   // all waves done reading before next stage
    }

    // epilogue: C/D layout col=lane&15, row=(lane>>4)*4+reg  [m89/m91]
    const int erow = (lane >> 4) * 4;
    const int ecol = lane & 15;
    #pragma unroll
    for (int fn = 0; fn < 4; ++fn) {
        const int gn = n0 + wn + fn * 16 + ecol;
        if (gn >= dout) continue;
        const float bv = bias[gn];
        #pragma unroll
        for (int fm = 0; fm < 4; ++fm) {
            #pragma unroll
            for (int r = 0; r < 4; ++r) {
                const size_t gm = m0 + wm + fm * 16 + erow + r;
                float v = acc[fm][fn][r] + bv;
                if (do_relu) v = fmaxf(v, 0.f);
                if (out_bf16) ((ushort_t*)outp)[gm * dout + gn] = f2bf(v);
                else          ((float*)outp)[gm * dout + gn] = v;
            }
        }
    }
}

// ---------------------------------------------------------------------------
extern "C" void kernel_launch(void* const* d_in, const int* in_sizes, int n_in,
                              void* d_out, int out_size, void* d_ws, size_t ws_size,
                              hipStream_t stream)
{
    const float* emb         = (const float*)d_in[0];
    const int*   input_nodes = (const int*)d_in[1];
    const int*   src0 = (const int*)d_in[2];
    const int*   dst0 = (const int*)d_in[3];
    const int*   src1 = (const int*)d_in[4];
    const int*   dst1 = (const int*)d_in[5];
    const int*   src2 = (const int*)d_in[6];
    const int*   dst2 = (const int*)d_in[7];
    const float* Ws0 = (const float*)d_in[8];
    const float* Wn0 = (const float*)d_in[9];
    const float* b0  = (const float*)d_in[10];
    const float* Ws1 = (const float*)d_in[11];
    const float* Wn1 = (const float*)d_in[12];
    const float* b1  = (const float*)d_in[13];
    const float* Ws2 = (const float*)d_in[14];
    const float* Wn2 = (const float*)d_in[15];
    const float* b2  = (const float*)d_in[16];
    float* out = (float*)d_out;

    // ---- Workspace layout (bf16 activations + int CSR scratch) ----
    ushort_t* us     = (ushort_t*)d_ws;
    ushort_t* embsel = us;                                   // 67584*128
    ushort_t* agg0   = embsel + (size_t)NDST0 * F0;          // 67584*128
    ushort_t* h1     = agg0 + (size_t)NDST0 * F0;            // 67584*256
    ushort_t* agg1   = h1 + (size_t)NDST0 * F1;              // 6144*256
    ushort_t* h2     = agg1 + (size_t)NDST1 * F1;            // 6144*256
    ushort_t* agg2   = h2 + (size_t)NDST1 * F1;              // 1024*256
    ushort_t* Bt0    = agg2 + (size_t)NDST2 * F1;            // 256 x 256
    ushort_t* Bt1    = Bt0 + 256 * 256;                      // 256 x 512
    ushort_t* Bt2    = Bt1 + 256 * 512;                      // 128 x 512 (rows 47..127 zero)

    int* ip   = (int*)(Bt2 + 128 * 512);
    int* cnt0 = ip;  ip += NDST0;
    int* cnt1 = ip;  ip += NDST1;
    int* cnt2 = ip;  ip += NDST2;
    const size_t zero_bytes = (size_t)(NDST0 + NDST1 + NDST2) * sizeof(int);
    int* rs0   = ip; ip += NDST0 + 1;
    int* rs1   = ip; ip += NDST1 + 1;
    int* rs2   = ip; ip += NDST2 + 1;
    int* rank0 = ip; ip += NEDGE0;
    int* rank1 = ip; ip += NEDGE1;
    int* rank2 = ip; ip += NEDGE2;
    int* esrc0 = ip; ip += NEDGE0;
    int* esrc1 = ip; ip += NEDGE1;
    int* esrc2 = ip; ip += NEDGE2;

    hipMemsetAsync(cnt0, 0, zero_bytes, stream);

    // Fused prep: sel_convert + wprep + hist-with-rank (after cnt memset)
    prep_all<<<SEL_BLOCKS + WPREP_BLOCKS + HIST_BLOCKS, 256, 0, stream>>>(
        emb, input_nodes, embsel,
        Ws0, Wn0, Ws1, Wn1, Ws2, Wn2, Bt0, Bt1, Bt2,
        dst0, dst1, dst2, cnt0, cnt1, cnt2, rank0, rank1, rank2);

    scan_all<<<3, 1024, 0, stream>>>(cnt0, rs0, cnt1, rs1, cnt2, rs2);
    fill_all<<<(NEDGE0 + NEDGE1 + NEDGE2 + 255) / 256, 256, 0, stream>>>(
        src0, dst0, src1, dst1, src2, dst2, input_nodes,
        rs0, rs1, rs2, rank0, rank1, rank2, esrc0, esrc1, esrc2);

    // ---- Layer 0: din=128 ----
    gather_f32<<<NDST0 / 8, 256, 0, stream>>>(emb, esrc0, rs0, cnt0, NDST0, F0, 5, agg0);
    mfma_gemm<<<dim3(256 / 128, NDST0 / 128), 256, 0, stream>>>(
        embsel, agg0, Bt0, b0, h1, F0, 256, /*out_bf16=*/1, /*relu=*/1);

    // ---- Layer 1: din=256 ----
    gather_bf16<<<NDST1 / 8, 256, 0, stream>>>(h1, esrc1, rs1, cnt1, NDST1, F1, 5, agg1);
    mfma_gemm<<<dim3(256 / 128, NDST1 / 128), 256, 0, stream>>>(
        h1, agg1, Bt1, b1, h2, F1, 256, /*out_bf16=*/1, /*relu=*/1);

    // ---- Layer 2: din=256, dout=47, no relu, fp32 out ----
    gather_bf16<<<NDST2 / 8, 256, 0, stream>>>(h2, esrc2, rs2, cnt2, NDST2, F1, 5, agg2);
    mfma_gemm<<<dim3(1, NDST2 / 128), 256, 0, stream>>>(
        h2, agg2, Bt2, b2, out, F1, NCLS, /*out_bf16=*/0, /*relu=*/0);
}